// Round 7
// baseline (730.753 us; speedup 1.0000x reference)
//
#include <hip/hip_runtime.h>
#include <stdint.h>

typedef __bf16 bf16x8 __attribute__((ext_vector_type(8)));
typedef float  f32x4  __attribute__((ext_vector_type(4)));

#define HH 384
#define WW 384
#define NPIX (HH*WW)
#define NC 3
#define NPATCH 576
#define EMB 768
#define PLEN 768
#define MLOC 32
#define KSTEPS 24
#define NLOC (64*576)
#define NTILES (NLOC/MLOC)       /* 1152 */
#define NT1 4                    /* GEMM1 n-tiles per wave (8 waves x 4 = 32) */
#define NT2 6                    /* GEMM2 n-tiles per wave (8 waves x 6 = 48) */
#define W1_UNITS (32*KSTEPS*64)
#define W2_UNITS (48*KSTEPS*64)
#define W2_OFF   (W1_UNITS*8)
#define PXP_OFF  ((W1_UNITS+W2_UNITS)*8)
#define NPIX_TOT (64*NPIX)
#define WBLKS  ((W1_UNITS + W2_UNITS) / 256)   /* 480  */
#define PXBLKS (NPIX_TOT / (256*4))            /* 36864 */

__device__ __forceinline__ uint16_t f2bf(float f) {
    uint32_t u = __builtin_bit_cast(uint32_t, f);
    u += 0x7FFFu + ((u >> 16) & 1u);
    return (uint16_t)(u >> 16);
}
__device__ __forceinline__ uint32_t pk2(float a, float b) {
    return (uint32_t)f2bf(a) | ((uint32_t)f2bf(b) << 16);
}
__device__ __forceinline__ float bf2f(uint16_t u) {
    return __builtin_bit_cast(float, (uint32_t)u << 16);
}

// Fused pre-pass: blocks [0,WBLKS) convert weights to MFMA-fragment bf16;
// blocks [WBLKS, WBLKS+PXBLKS) pack pixels NCHW f32 -> NHWC bf16 (8B/px).
__global__ __launch_bounds__(256)
void prepass(const float* __restrict__ offw, const float* __restrict__ projw,
             const float* __restrict__ pix, uint16_t* __restrict__ wz) {
    int b = blockIdx.x;
    if (b < WBLKS) {
        int u = b * 256 + threadIdx.x;
        const float* src;
        int uu;
        if (u < W1_UNITS) { src = offw; uu = u; }
        else              { src = projw; uu = u - W1_UNITS; }
        int lane = uu & 63;
        int t    = uu >> 6;
        int ks   = t % KSTEPS;
        int nt   = t / KSTEPS;
        int n    = nt * 16 + (lane & 15);
        int k0   = ks * 32 + (lane >> 4) * 8;
        const float4* s4 = (const float4*)(src + (size_t)n * PLEN + k0);
        float4 v0 = s4[0], v1 = s4[1];
        uint4 w;
        w.x = pk2(v0.x, v0.y); w.y = pk2(v0.z, v0.w);
        w.z = pk2(v1.x, v1.y); w.w = pk2(v1.z, v1.w);
        *(uint4*)(wz + (size_t)u * 8) = w;
    } else {
        int idx  = (b - WBLKS) * 256 + threadIdx.x;   // 4-pixel group
        int base = idx * 4;
        int im = base / NPIX;
        int yx = base - im * NPIX;                    // NPIX % 4 == 0
        const float* p = pix + (size_t)im * NC * NPIX + yx;
        float4 c0 = *(const float4*)p;
        float4 c1 = *(const float4*)(p + NPIX);
        float4 c2 = *(const float4*)(p + 2 * NPIX);
        uint4 o0, o1;
        o0.x = pk2(c0.x, c1.x); o0.y = (uint32_t)f2bf(c2.x);
        o0.z = pk2(c0.y, c1.y); o0.w = (uint32_t)f2bf(c2.y);
        o1.x = pk2(c0.z, c1.z); o1.y = (uint32_t)f2bf(c2.z);
        o1.z = pk2(c0.w, c1.w); o1.w = (uint32_t)f2bf(c2.w);
        uint16_t* dst = wz + PXP_OFF + (size_t)base * 4;
        *(uint4*)dst       = o0;
        *(uint4*)(dst + 8) = o1;
    }
}

template<bool USE_WS>
__global__ __launch_bounds__(512, 6)
void fused_kernel(const float* __restrict__ pix,
                  const float* __restrict__ offw,
                  const float* __restrict__ offb,
                  const float* __restrict__ projw,
                  const float* __restrict__ projb,
                  const uint16_t* __restrict__ wz,
                  float* __restrict__ out) {
    // 48 KB only: packed (dy,dx) offsets are OVERLAID into the first 1 KB of
    // each As row after GEMM1 (patch data dead there), so 3 blocks/CU fit.
    __shared__ __align__(16) uint16_t As[MLOC][PLEN];

    const int tid  = threadIdx.x;
    const int wv   = tid >> 6;
    const int lane = tid & 63;
    const int lr   = lane & 15;
    const int lg   = lane >> 4;
    const int sw0  = (lr & 7) << 3;
    const int even = ((lane & 1) == 0);

    // bijective XCD swizzle: 1152 = 8 x 144
    int bid = (int)blockIdx.x;
    const int tile = (bid & 7) * 144 + (bid >> 3);

    const int loc0 = tile * MLOC;
    const int bimg = loc0 / NPATCH;
    const int p0   = loc0 - bimg * NPATCH;
    const float*    __restrict__ pb  = pix + (size_t)bimg * NC * NPIX;
    const uint16_t* __restrict__ pxp = wz + PXP_OFF + (size_t)bimg * NPIX * 4;

    // ---------------- Phase A: stage 32 patches into As (swizzled) ---------
    if (USE_WS) {
        // From NHWC bf16 pxp: unit = (i, loc, xg); lane-contiguous in (loc,xg)
        // -> 1KB contiguous global per wave-instr; u32 bank = i*8+xg ^ (loc&7)<<2.
        #pragma unroll
        for (int uu = 0; uu < 8; ++uu) {
            int unit = uu * 512 + tid;          // 0..4095
            int xg   = unit & 7;                // 2-px group within row
            int loc  = (unit >> 3) & 31;
            int i    = unit >> 8;               // 0..15
            int p  = p0 + loc;
            int ho = p / 24;
            int wo = p - ho * 24;
            const uint16_t* g = pxp + ((size_t)(ho * 16 + i) * WW + wo * 16 + xg * 2) * 4;
            uint4 d = *(const uint4*)g;         // px0:(c01,c2) px1:(c01,c2)
            uint32_t ch0 = (d.x & 0xFFFFu) | (d.z << 16);
            uint32_t ch1 = (d.x >> 16)     | (d.z & 0xFFFF0000u);
            uint32_t ch2 = (d.y & 0xFFFFu) | (d.w << 16);
            int k   = i * 16 + xg * 2;
            int swl = (loc & 7) << 3;
            uint32_t* row = (uint32_t*)&As[loc][0];
            row[((      k) ^ swl) >> 1] = ch0;
            row[((256 + k) ^ swl) >> 1] = ch1;
            row[((512 + k) ^ swl) >> 1] = ch2;
        }
    } else {
        #pragma unroll
        for (int uu = 0; uu < 6; ++uu) {
            int unit = tid + uu * 512;             // 0..3071
            int loc  = unit / 96;
            int k8   = (unit - loc * 96) * 8;
            int c  = k8 >> 8;
            int i  = (k8 >> 4) & 15;
            int j  = k8 & 15;
            int p  = p0 + loc;
            int ho = p / 24;
            int wo = p - ho * 24;
            const float* g = pb + ((size_t)c * HH + ho * 16 + i) * WW + wo * 16 + j;
            float4 v0 = *(const float4*)g;
            float4 v1 = *(const float4*)(g + 4);
            uint4 w;
            w.x = pk2(v0.x, v0.y); w.y = pk2(v0.z, v0.w);
            w.z = pk2(v1.x, v1.y); w.w = pk2(v1.z, v1.w);
            *(uint4*)&As[loc][k8 ^ ((loc & 7) << 3)] = w;
        }
    }

    // ---------------- GEMM1: offsets [32 x 512], B double-buffered ---------
    auto ldb1 = [&](int ntg, int ks) -> bf16x8 {
        if (USE_WS) {
            return *(const bf16x8*)(wz + ((size_t)((ntg * KSTEPS + ks) * 64 + lane)) * 8);
        } else {
            int n = ntg * 16 + lr;
            const float4* s4 = (const float4*)(offw + (size_t)n * PLEN + ks * 32 + lg * 8);
            float4 v0 = s4[0], v1 = s4[1];
            uint4 uq = {pk2(v0.x,v0.y), pk2(v0.z,v0.w), pk2(v1.x,v1.y), pk2(v1.z,v1.w)};
            return __builtin_bit_cast(bf16x8, uq);
        }
    };
    bf16x8 b1a[NT1], b1b[NT1];
    #pragma unroll
    for (int nt = 0; nt < NT1; ++nt) b1a[nt] = ldb1(wv * NT1 + nt, 0);
    __syncthreads();                       // stage visible

    f32x4 acc1[2][NT1];
    #pragma unroll
    for (int nt = 0; nt < NT1; ++nt) {
        float bz = offb[(wv * NT1 + nt) * 16 + lr];
        f32x4 z = {bz, bz, bz, bz};
        acc1[0][nt] = z; acc1[1][nt] = z;
    }
    #pragma unroll 1
    for (int ks2 = 0; ks2 < KSTEPS / 2; ++ks2) {
        const int ks0 = ks2 * 2;
        {
            #pragma unroll
            for (int nt = 0; nt < NT1; ++nt) b1b[nt] = ldb1(wv * NT1 + nt, ks0 + 1);
            int ke = (ks0 * 32 + lg * 8) ^ sw0;
            bf16x8 a0 = *(const bf16x8*)&As[lr][ke];
            bf16x8 a1 = *(const bf16x8*)&As[16 + lr][ke];
            __builtin_amdgcn_s_setprio(1);
            #pragma unroll
            for (int nt = 0; nt < NT1; ++nt) {
                acc1[0][nt] = __builtin_amdgcn_mfma_f32_16x16x32_bf16(a0, b1a[nt], acc1[0][nt], 0, 0, 0);
                acc1[1][nt] = __builtin_amdgcn_mfma_f32_16x16x32_bf16(a1, b1a[nt], acc1[1][nt], 0, 0, 0);
            }
            __builtin_amdgcn_s_setprio(0);
        }
        {
            int ksn = (ks0 + 2 < KSTEPS) ? ks0 + 2 : 0;
            #pragma unroll
            for (int nt = 0; nt < NT1; ++nt) b1a[nt] = ldb1(wv * NT1 + nt, ksn);
            int ke = ((ks0 + 1) * 32 + lg * 8) ^ sw0;
            bf16x8 a0 = *(const bf16x8*)&As[lr][ke];
            bf16x8 a1 = *(const bf16x8*)&As[16 + lr][ke];
            __builtin_amdgcn_s_setprio(1);
            #pragma unroll
            for (int nt = 0; nt < NT1; ++nt) {
                acc1[0][nt] = __builtin_amdgcn_mfma_f32_16x16x32_bf16(a0, b1b[nt], acc1[0][nt], 0, 0, 0);
                acc1[1][nt] = __builtin_amdgcn_mfma_f32_16x16x32_bf16(a1, b1b[nt], acc1[1][nt], 0, 0, 0);
            }
            __builtin_amdgcn_s_setprio(0);
        }
    }
    __syncthreads();   // ALL waves done reading patch A-matrix (overlay next)

    // ---------------- Scatter (dy,dx) -> overlay in As rows (bytes 0..1023) -
    // acc1 D layout: col n = (wv*NT1+nt)*16 + lr, row = mt*16 + lg*4 + r.
    // n=2q dy(q), n=2q+1 dx(q); shfl_xor(1) pairs; even lanes own sub-tiles
    // {0,1}, odd {2,3}.
    #pragma unroll
    for (int nt = 0; nt < NT1; ++nt)
      #pragma unroll
      for (int mt = 0; mt < 2; ++mt)
        #pragma unroll
        for (int r = 0; r < 4; ++r) {
            float v  = acc1[mt][nt][r];
            float pv = __shfl_xor(v, 1);
            if ((nt < 2) == (even != 0)) {
                int s   = nt & 1;
                int loc = mt * 16 + lg * 4 + r;
                int q   = (wv * NT1 + (even ? 0 : 2) + s) * 8 + (lr >> 1);
                float dy = even ? v  : pv;
                float dx = even ? pv : v;
                ((uint32_t*)&As[loc][0])[q] = pk2(dy, dx);
            }
        }
    __syncthreads();   // offsets visible

    // ---------------- Phase C: locality-mapped gather ----------------------
    // Wave wv owns rows L = wv*4..wv*4+3; lanes cover 64 contiguous sample
    // positions. Read row's 4 packed offsets into regs BEFORE overwriting it.
    {
        #pragma unroll
        for (int li = 0; li < 4; ++li) {
            const int L  = wv * 4 + li;
            const int p  = p0 + L;
            const int ho = p / 24;
            const int wo = p - ho * 24;
            const int swl = (L & 7) << 3;
            const int by = ho * 16;
            const int bx = wo * 16;
            const uint32_t* rowu = (const uint32_t*)&As[L][0];
            uint32_t od0 = rowu[       lane];
            uint32_t od1 = rowu[ 64 +  lane];
            uint32_t od2 = rowu[128 +  lane];
            uint32_t od3 = rowu[192 +  lane];
            #pragma unroll
            for (int s4 = 0; s4 < 4; ++s4) {
                const int q  = s4 * 64 + lane;
                const int qi = q >> 4;
                const int qj = q & 15;
                uint32_t od = (s4 == 0) ? od0 : (s4 == 1) ? od1 : (s4 == 2) ? od2 : od3;
                float dy = bf2f((uint16_t)od);
                float dx = bf2f((uint16_t)(od >> 16));
                float py = (float)(by + qi) + dy;
                float px = (float)(bx + qj) + dx;
                float y0f = floorf(py), x0f = floorf(px);
                float wy1 = py - y0f, wy0 = 1.f - wy1;
                float wx1 = px - x0f, wx0 = 1.f - wx1;
                int y0 = (int)y0f, x0 = (int)x0f;
                float s0 = 0.f, s1 = 0.f, s2 = 0.f;
                #pragma unroll
                for (int cy = 0; cy < 2; ++cy) {
                    int yy = y0 + cy;
                    if ((unsigned)yy < (unsigned)HH) {
                        float wy = cy ? wy1 : wy0;
                        #pragma unroll
                        for (int cx = 0; cx < 2; ++cx) {
                            int xx = x0 + cx;
                            if ((unsigned)xx < (unsigned)WW) {
                                float w = wy * (cx ? wx1 : wx0);
                                float v0, v1, v2;
                                if (USE_WS) {
                                    uint2 d = *(const uint2*)(pxp + ((size_t)yy * WW + xx) * 4);
                                    v0 = bf2f((uint16_t)d.x);
                                    v1 = bf2f((uint16_t)(d.x >> 16));
                                    v2 = bf2f((uint16_t)d.y);
                                } else {
                                    const float* cp = pb + yy * WW + xx;
                                    v0 = cp[0]; v1 = cp[NPIX]; v2 = cp[2 * NPIX];
                                }
                                s0 += w * v0; s1 += w * v1; s2 += w * v2;
                            }
                        }
                    }
                }
                As[L][(      q) ^ swl] = f2bf(s0);
                As[L][(256 + q) ^ swl] = f2bf(s1);
                As[L][(512 + q) ^ swl] = f2bf(s2);
            }
        }
    }

    // ---------------- GEMM2: out [32 x 768], B double-buffered -------------
    auto ldb2 = [&](int ntg, int ks) -> bf16x8 {
        if (USE_WS) {
            return *(const bf16x8*)(wz + W2_OFF + ((size_t)((ntg * KSTEPS + ks) * 64 + lane)) * 8);
        } else {
            int n = ntg * 16 + lr;
            const float4* s4 = (const float4*)(projw + (size_t)n * PLEN + ks * 32 + lg * 8);
            float4 v0 = s4[0], v1 = s4[1];
            uint4 uq = {pk2(v0.x,v0.y), pk2(v0.z,v0.w), pk2(v1.x,v1.y), pk2(v1.z,v1.w)};
            return __builtin_bit_cast(bf16x8, uq);
        }
    };
    bf16x8 b2a[NT2], b2b[NT2];
    #pragma unroll
    for (int nt = 0; nt < NT2; ++nt) b2a[nt] = ldb2(wv * NT2 + nt, 0);
    __syncthreads();                       // sampled writes visible

    f32x4 acc2[2][NT2];
    #pragma unroll
    for (int nt = 0; nt < NT2; ++nt) {
        float bz = projb[(wv * NT2 + nt) * 16 + lr];
        f32x4 z = {bz, bz, bz, bz};
        acc2[0][nt] = z; acc2[1][nt] = z;
    }
    #pragma unroll 1
    for (int ks2 = 0; ks2 < KSTEPS / 2; ++ks2) {
        const int ks0 = ks2 * 2;
        {
            #pragma unroll
            for (int nt = 0; nt < NT2; ++nt) b2b[nt] = ldb2(wv * NT2 + nt, ks0 + 1);
            int ke = (ks0 * 32 + lg * 8) ^ sw0;
            bf16x8 a0 = *(const bf16x8*)&As[lr][ke];
            bf16x8 a1 = *(const bf16x8*)&As[16 + lr][ke];
            __builtin_amdgcn_s_setprio(1);
            #pragma unroll
            for (int nt = 0; nt < NT2; ++nt) {
                acc2[0][nt] = __builtin_amdgcn_mfma_f32_16x16x32_bf16(a0, b2a[nt], acc2[0][nt], 0, 0, 0);
                acc2[1][nt] = __builtin_amdgcn_mfma_f32_16x16x32_bf16(a1, b2a[nt], acc2[1][nt], 0, 0, 0);
            }
            __builtin_amdgcn_s_setprio(0);
        }
        {
            int ksn = (ks0 + 2 < KSTEPS) ? ks0 + 2 : 0;
            #pragma unroll
            for (int nt = 0; nt < NT2; ++nt) b2a[nt] = ldb2(wv * NT2 + nt, ksn);
            int ke = ((ks0 + 1) * 32 + lg * 8) ^ sw0;
            bf16x8 a0 = *(const bf16x8*)&As[lr][ke];
            bf16x8 a1 = *(const bf16x8*)&As[16 + lr][ke];
            __builtin_amdgcn_s_setprio(1);
            #pragma unroll
            for (int nt = 0; nt < NT2; ++nt) {
                acc2[0][nt] = __builtin_amdgcn_mfma_f32_16x16x32_bf16(a0, b2b[nt], acc2[0][nt], 0, 0, 0);
                acc2[1][nt] = __builtin_amdgcn_mfma_f32_16x16x32_bf16(a1, b2b[nt], acc2[1][nt], 0, 0, 0);
            }
            __builtin_amdgcn_s_setprio(0);
        }
    }

    // ---------------- Epilogue: direct f32 stores --------------------------
    #pragma unroll
    for (int mt = 0; mt < 2; ++mt)
      #pragma unroll
      for (int r = 0; r < 4; ++r) {
        int flat = loc0 + mt * 16 + lg * 4 + r;
        float* op = out + (size_t)flat * EMB;
        #pragma unroll
        for (int nt = 0; nt < NT2; ++nt)
            op[(wv * NT2 + nt) * 16 + lr] = acc2[mt][nt][r];
      }
}

extern "C" void kernel_launch(void* const* d_in, const int* in_sizes, int n_in,
                              void* d_out, int out_size, void* d_ws, size_t ws_size,
                              hipStream_t stream) {
    const float* pix   = (const float*)d_in[0];
    const float* offw  = (const float*)d_in[1];
    const float* offb  = (const float*)d_in[2];
    const float* projw = (const float*)d_in[3];
    const float* projb = (const float*)d_in[4];
    float* out = (float*)d_out;
    uint16_t* wz = (uint16_t*)d_ws;

    const size_t ws_needed = (size_t)(W1_UNITS + W2_UNITS) * 16 + (size_t)NPIX_TOT * 8;

    if (ws_size >= ws_needed) {
        prepass<<<WBLKS + PXBLKS, 256, 0, stream>>>(offw, projw, pix, wz);
        fused_kernel<true><<<NTILES, 512, 0, stream>>>(pix, offw, offb, projw, projb, wz, out);
    } else {
        fused_kernel<false><<<NTILES, 512, 0, stream>>>(pix, offw, offb, projw, projb, wz, out);
    }
}

// Round 8
// 215.588 us; speedup vs baseline: 3.3896x; 3.3896x over previous
//
#include <hip/hip_runtime.h>
#include <stdint.h>

typedef __bf16 bf16x8 __attribute__((ext_vector_type(8)));
typedef float  f32x4  __attribute__((ext_vector_type(4)));

#define HH 384
#define WW 384
#define NPIX (HH*WW)
#define NC 3
#define NPATCH 576
#define EMB 768
#define PLEN 768
#define MLOC 32
#define KSTEPS 24
#define NLOC (64*576)
#define NTILES (NLOC/MLOC)       /* 1152 */
#define NT1 4                    /* GEMM1 n-tiles per wave (8 waves x 4 = 32) */
#define W1_UNITS (32*KSTEPS*64)
#define W2_UNITS (48*KSTEPS*64)
#define W2_OFF   (W1_UNITS*8)
#define SA_OFF   ((W1_UNITS+W2_UNITS)*8)   /* u16 offset of sampled matrix */
#define WBLKS  ((W1_UNITS + W2_UNITS) / 256)   /* 480 */

__device__ __forceinline__ uint16_t f2bf(float f) {
    uint32_t u = __builtin_bit_cast(uint32_t, f);
    u += 0x7FFFu + ((u >> 16) & 1u);
    return (uint16_t)(u >> 16);
}
__device__ __forceinline__ uint32_t pk2(float a, float b) {
    return (uint32_t)f2bf(a) | ((uint32_t)f2bf(b) << 16);
}
__device__ __forceinline__ float bf2f(uint16_t u) {
    return __builtin_bit_cast(float, (uint32_t)u << 16);
}

// Weights -> bf16 in MFMA-fragment order:
// unit u -> (nt, ks, lane); n = nt*16 + (lane&15), k = ks*32 + (lane>>4)*8 + e
__global__ __launch_bounds__(256)
void prepass_w(const float* __restrict__ offw, const float* __restrict__ projw,
               uint16_t* __restrict__ wz) {
    int u = blockIdx.x * 256 + threadIdx.x;
    const float* src;
    int uu;
    if (u < W1_UNITS) { src = offw; uu = u; }
    else              { src = projw; uu = u - W1_UNITS; }
    int lane = uu & 63;
    int t    = uu >> 6;
    int ks   = t % KSTEPS;
    int nt   = t / KSTEPS;
    int n    = nt * 16 + (lane & 15);
    int k0   = ks * 32 + (lane >> 4) * 8;
    const float4* s4 = (const float4*)(src + (size_t)n * PLEN + k0);
    float4 v0 = s4[0], v1 = s4[1];
    uint4 w;
    w.x = pk2(v0.x, v0.y); w.y = pk2(v0.z, v0.w);
    w.z = pk2(v1.x, v1.y); w.w = pk2(v1.z, v1.w);
    *(uint4*)(wz + (size_t)u * 8) = w;
}

// ======================= K1: offset conv ==================================
// Stage 32 patches -> LDS (bf16, swizzled), GEMM1, write packed (dy,dx) u32
// into the first 1KB of each sampled-matrix row in ws.
__global__ __launch_bounds__(512, 4)
void k1_offsets(const float* __restrict__ pix,
                const float* __restrict__ offb,
                const uint16_t* __restrict__ wz,
                uint16_t* __restrict__ sa) {
    __shared__ __align__(16) uint16_t As[MLOC][PLEN];   // 48 KB

    const int tid  = threadIdx.x;
    const int wv   = tid >> 6;
    const int lane = tid & 63;
    const int lr   = lane & 15;
    const int lg   = lane >> 4;
    const int sw0  = (lr & 7) << 3;
    const int even = ((lane & 1) == 0);

    int bid = (int)blockIdx.x;                 // bijective XCD swizzle 8x144
    const int tile = (bid & 7) * 144 + (bid >> 3);
    const int loc0 = tile * MLOC;
    const int bimg = loc0 / NPATCH;
    const int p0   = loc0 - bimg * NPATCH;
    const float* __restrict__ pb = pix + (size_t)bimg * NC * NPIX;

    // Phase A: stage (f32 -> bf16, XOR-swizzled)
    #pragma unroll
    for (int uu = 0; uu < 6; ++uu) {
        int unit = tid + uu * 512;
        int loc  = unit / 96;
        int k8   = (unit - loc * 96) * 8;
        int c  = k8 >> 8;
        int i  = (k8 >> 4) & 15;
        int j  = k8 & 15;
        int p  = p0 + loc;
        int ho = p / 24;
        int wo = p - ho * 24;
        const float* g = pb + ((size_t)c * HH + ho * 16 + i) * WW + wo * 16 + j;
        float4 v0 = *(const float4*)g;
        float4 v1 = *(const float4*)(g + 4);
        uint4 w;
        w.x = pk2(v0.x, v0.y); w.y = pk2(v0.z, v0.w);
        w.z = pk2(v1.x, v1.y); w.w = pk2(v1.z, v1.w);
        *(uint4*)&As[loc][k8 ^ ((loc & 7) << 3)] = w;
    }

    auto ldb1 = [&](int ntg, int ks) -> bf16x8 {
        return *(const bf16x8*)(wz + ((size_t)((ntg * KSTEPS + ks) * 64 + lane)) * 8);
    };
    bf16x8 b1a[NT1], b1b[NT1];
    #pragma unroll
    for (int nt = 0; nt < NT1; ++nt) b1a[nt] = ldb1(wv * NT1 + nt, 0);
    __syncthreads();

    f32x4 acc1[2][NT1];
    #pragma unroll
    for (int nt = 0; nt < NT1; ++nt) {
        float bz = offb[(wv * NT1 + nt) * 16 + lr];
        f32x4 z = {bz, bz, bz, bz};
        acc1[0][nt] = z; acc1[1][nt] = z;
    }
    #pragma unroll 1
    for (int ks2 = 0; ks2 < KSTEPS / 2; ++ks2) {
        const int ks0 = ks2 * 2;
        {
            #pragma unroll
            for (int nt = 0; nt < NT1; ++nt) b1b[nt] = ldb1(wv * NT1 + nt, ks0 + 1);
            int ke = (ks0 * 32 + lg * 8) ^ sw0;
            bf16x8 a0 = *(const bf16x8*)&As[lr][ke];
            bf16x8 a1 = *(const bf16x8*)&As[16 + lr][ke];
            #pragma unroll
            for (int nt = 0; nt < NT1; ++nt) {
                acc1[0][nt] = __builtin_amdgcn_mfma_f32_16x16x32_bf16(a0, b1a[nt], acc1[0][nt], 0, 0, 0);
                acc1[1][nt] = __builtin_amdgcn_mfma_f32_16x16x32_bf16(a1, b1a[nt], acc1[1][nt], 0, 0, 0);
            }
        }
        {
            int ksn = (ks0 + 2 < KSTEPS) ? ks0 + 2 : 0;
            #pragma unroll
            for (int nt = 0; nt < NT1; ++nt) b1a[nt] = ldb1(wv * NT1 + nt, ksn);
            int ke = ((ks0 + 1) * 32 + lg * 8) ^ sw0;
            bf16x8 a0 = *(const bf16x8*)&As[lr][ke];
            bf16x8 a1 = *(const bf16x8*)&As[16 + lr][ke];
            #pragma unroll
            for (int nt = 0; nt < NT1; ++nt) {
                acc1[0][nt] = __builtin_amdgcn_mfma_f32_16x16x32_bf16(a0, b1b[nt], acc1[0][nt], 0, 0, 0);
                acc1[1][nt] = __builtin_amdgcn_mfma_f32_16x16x32_bf16(a1, b1b[nt], acc1[1][nt], 0, 0, 0);
            }
        }
    }

    // Pack (dy,dx) via shfl_xor and write to ws (first 1KB of each row).
    // D layout: col n = (wv*NT1+nt)*16 + lr, row = mt*16 + lg*4 + r.
    #pragma unroll
    for (int nt = 0; nt < NT1; ++nt)
      #pragma unroll
      for (int mt = 0; mt < 2; ++mt)
        #pragma unroll
        for (int r = 0; r < 4; ++r) {
            float v  = acc1[mt][nt][r];
            float pv = __shfl_xor(v, 1);
            if ((nt < 2) == (even != 0)) {
                int s   = nt & 1;
                int loc = mt * 16 + lg * 4 + r;
                int q   = (wv * NT1 + (even ? 0 : 2) + s) * 8 + (lr >> 1);
                float dy = even ? v  : pv;
                float dx = even ? pv : v;
                ((uint32_t*)(sa + (size_t)(loc0 + loc) * PLEN))[q] = pk2(dy, dx);
            }
        }
}

// ======================= K2: bilinear gather ==============================
// No LDS, no barriers. Wave owns 4 rows; reads the row's 256 packed offsets
// into regs (vmcnt(0) before stores: stores alias the offset bytes), gathers
// from f32 NCHW pix, writes linear bf16 rows (coalesced 128B stores).
__global__ __launch_bounds__(512)
void k2_gather(const float* __restrict__ pix, uint16_t* __restrict__ sa) {
    const int tid  = threadIdx.x;
    const int wv   = tid >> 6;
    const int lane = tid & 63;

    int bid = (int)blockIdx.x;
    const int tile = (bid & 7) * 144 + (bid >> 3);
    const int loc0 = tile * MLOC;
    const int bimg = loc0 / NPATCH;
    const int p0   = loc0 - bimg * NPATCH;
    const float* __restrict__ pb = pix + (size_t)bimg * NC * NPIX;

    #pragma unroll
    for (int li = 0; li < 4; ++li) {
        const int L   = wv * 4 + li;
        const int p   = p0 + L;
        const int ho  = p / 24;
        const int wo  = p - ho * 24;
        const int by  = ho * 16;
        const int bx  = wo * 16;
        uint16_t* row = sa + (size_t)(loc0 + L) * PLEN;
        const uint32_t* rowu = (const uint32_t*)row;
        uint32_t od0 = rowu[       lane];
        uint32_t od1 = rowu[ 64 +  lane];
        uint32_t od2 = rowu[128 +  lane];
        uint32_t od3 = rowu[192 +  lane];
        asm volatile("s_waitcnt vmcnt(0)" ::: "memory");   // loads before aliasing stores
        #pragma unroll
        for (int s4 = 0; s4 < 4; ++s4) {
            const int q  = s4 * 64 + lane;
            const int qi = q >> 4;
            const int qj = q & 15;
            uint32_t od = (s4 == 0) ? od0 : (s4 == 1) ? od1 : (s4 == 2) ? od2 : od3;
            float dy = bf2f((uint16_t)od);
            float dx = bf2f((uint16_t)(od >> 16));
            float py = (float)(by + qi) + dy;
            float px = (float)(bx + qj) + dx;
            float y0f = floorf(py), x0f = floorf(px);
            float wy1 = py - y0f, wy0 = 1.f - wy1;
            float wx1 = px - x0f, wx0 = 1.f - wx1;
            int y0 = (int)y0f, x0 = (int)x0f;
            float s0 = 0.f, s1 = 0.f, s2 = 0.f;
            #pragma unroll
            for (int cy = 0; cy < 2; ++cy) {
                int yy = y0 + cy;
                if ((unsigned)yy < (unsigned)HH) {
                    float wy = cy ? wy1 : wy0;
                    #pragma unroll
                    for (int cx = 0; cx < 2; ++cx) {
                        int xx = x0 + cx;
                        if ((unsigned)xx < (unsigned)WW) {
                            float w = wy * (cx ? wx1 : wx0);
                            const float* cp = pb + yy * WW + xx;
                            s0 += w * cp[0];
                            s1 += w * cp[NPIX];
                            s2 += w * cp[2 * NPIX];
                        }
                    }
                }
            }
            row[      q] = f2bf(s0);
            row[256 + q] = f2bf(s1);
            row[512 + q] = f2bf(s2);
        }
    }
}

// ======================= K3: projection GEMM ==============================
// out[36864 x 768] = sa[36864 x 768] * W2^T + bias. 128x128 tile, BK=64,
// 4 waves (2x2), reg-staged double-buffered A (XOR-swizzled), B from wz.
__global__ __launch_bounds__(256, 3)
void k3_proj(const uint16_t* __restrict__ wz, const float* __restrict__ projb,
             float* __restrict__ out) {
    __shared__ __align__(16) uint16_t Asb[2][128][64];   // 32 KB

    const int tid  = threadIdx.x;
    const int wv   = tid >> 6;
    const int lane = tid & 63;
    const int lr   = lane & 15;
    const int lg   = lane >> 4;
    const int wm   = wv >> 1;
    const int wn   = wv & 1;

    int bid = (int)blockIdx.x;                  // 1728 = 8 x 216 bijective
    const int fin   = (bid & 7) * 216 + (bid >> 3);
    const int mtile = fin / 6;
    const int ncol  = fin - mtile * 6;
    const int loc0  = mtile * 128;
    const int n0    = ncol * 128;
    const uint16_t* __restrict__ sa = wz + SA_OFF;

    const int srow = tid >> 1;        // 0..127
    const int shalf = tid & 1;
    const int srb = srow & 7;
    const uint16_t* sg = sa + (size_t)(loc0 + srow) * PLEN + shalf * 32;

    uint4 r0, r1, r2, r3;
    auto st_load = [&](int t) {
        const uint16_t* g = sg + t * 64;
        r0 = *(const uint4*)g;
        r1 = *(const uint4*)(g + 8);
        r2 = *(const uint4*)(g + 16);
        r3 = *(const uint4*)(g + 24);
    };
    auto st_write = [&](int buf) {
        uint16_t* dst = &Asb[buf][srow][0];
        *(uint4*)(dst + (((shalf * 4 + 0) ^ srb) * 8)) = r0;
        *(uint4*)(dst + (((shalf * 4 + 1) ^ srb) * 8)) = r1;
        *(uint4*)(dst + (((shalf * 4 + 2) ^ srb) * 8)) = r2;
        *(uint4*)(dst + (((shalf * 4 + 3) ^ srb) * 8)) = r3;
    };
    auto ldb = [&](int nt, int ks) -> bf16x8 {
        int ntg = ncol * 8 + wn * 4 + nt;
        return *(const bf16x8*)(wz + W2_OFF + ((size_t)((ntg * KSTEPS + ks) * 64 + lane)) * 8);
    };

    f32x4 acc[4][4];
    #pragma unroll
    for (int nt = 0; nt < 4; ++nt) {
        float bz = projb[n0 + wn * 64 + nt * 16 + lr];
        f32x4 z = {bz, bz, bz, bz};
        #pragma unroll
        for (int mi = 0; mi < 4; ++mi) acc[mi][nt] = z;
    }

    bf16x8 ba[4], bb[4];
    st_load(0);
    st_write(0);
    #pragma unroll
    for (int nt = 0; nt < 4; ++nt) ba[nt] = ldb(nt, 0);
    __syncthreads();

    #pragma unroll 1
    for (int t = 0; t < 12; ++t) {
        const int cur = t & 1;
        if (t < 11) st_load(t + 1);
        // ks2 = 0 (consume ba, prefetch bb)
        {
            #pragma unroll
            for (int nt = 0; nt < 4; ++nt) bb[nt] = ldb(nt, t * 2 + 1);
            bf16x8 a0, a1, a2, a3;
            {
                const int u = ((0 * 4 + lg) ^ (lr & 7)) * 8;
                a0 = *(const bf16x8*)&Asb[cur][wm * 64 +  0 + lr][u];
                a1 = *(const bf16x8*)&Asb[cur][wm * 64 + 16 + lr][u];
                a2 = *(const bf16x8*)&Asb[cur][wm * 64 + 32 + lr][u];
                a3 = *(const bf16x8*)&Asb[cur][wm * 64 + 48 + lr][u];
            }
            #pragma unroll
            for (int nt = 0; nt < 4; ++nt) {
                acc[0][nt] = __builtin_amdgcn_mfma_f32_16x16x32_bf16(a0, ba[nt], acc[0][nt], 0, 0, 0);
                acc[1][nt] = __builtin_amdgcn_mfma_f32_16x16x32_bf16(a1, ba[nt], acc[1][nt], 0, 0, 0);
                acc[2][nt] = __builtin_amdgcn_mfma_f32_16x16x32_bf16(a2, ba[nt], acc[2][nt], 0, 0, 0);
                acc[3][nt] = __builtin_amdgcn_mfma_f32_16x16x32_bf16(a3, ba[nt], acc[3][nt], 0, 0, 0);
            }
        }
        // ks2 = 1 (consume bb, prefetch ba for next t)
        {
            if (t < 11) {
                #pragma unroll
                for (int nt = 0; nt < 4; ++nt) ba[nt] = ldb(nt, t * 2 + 2);
            }
            bf16x8 a0, a1, a2, a3;
            {
                const int u = ((1 * 4 + lg) ^ (lr & 7)) * 8;
                a0 = *(const bf16x8*)&Asb[cur][wm * 64 +  0 + lr][u];
                a1 = *(const bf16x8*)&Asb[cur][wm * 64 + 16 + lr][u];
                a2 = *(const bf16x8*)&Asb[cur][wm * 64 + 32 + lr][u];
                a3 = *(const bf16x8*)&Asb[cur][wm * 64 + 48 + lr][u];
            }
            #pragma unroll
            for (int nt = 0; nt < 4; ++nt) {
                acc[0][nt] = __builtin_amdgcn_mfma_f32_16x16x32_bf16(a0, bb[nt], acc[0][nt], 0, 0, 0);
                acc[1][nt] = __builtin_amdgcn_mfma_f32_16x16x32_bf16(a1, bb[nt], acc[1][nt], 0, 0, 0);
                acc[2][nt] = __builtin_amdgcn_mfma_f32_16x16x32_bf16(a2, bb[nt], acc[2][nt], 0, 0, 0);
                acc[3][nt] = __builtin_amdgcn_mfma_f32_16x16x32_bf16(a3, bb[nt], acc[3][nt], 0, 0, 0);
            }
        }
        if (t < 11) st_write(cur ^ 1);
        __syncthreads();
    }

    // Epilogue
    #pragma unroll
    for (int mi = 0; mi < 4; ++mi)
      #pragma unroll
      for (int r = 0; r < 4; ++r) {
        int rowg = loc0 + wm * 64 + mi * 16 + lg * 4 + r;
        float* op = out + (size_t)rowg * EMB + n0 + wn * 64;
        #pragma unroll
        for (int nt = 0; nt < 4; ++nt)
            op[nt * 16 + lr] = acc[mi][nt][r];
      }
}

// ======================= fallback (tiny ws) ===============================
__global__ __launch_bounds__(256)
void fallback_kernel(const float* __restrict__ pix, const float* __restrict__ offw,
                     const float* __restrict__ offb, const float* __restrict__ projw,
                     const float* __restrict__ projb, float* __restrict__ out) {
    __shared__ float buf[8][PLEN];
    const int tid = threadIdx.x;
    const int loc0 = blockIdx.x * 8;
    #pragma unroll
    for (int r = 0; r < 6; ++r) {
        int item = tid + r * 256;
        int l = item / 192, k = (item - l * 192) * 4;
        int c = k >> 8, i = (k >> 4) & 15, j = k & 15;
        int flat = loc0 + l, b = flat / NPATCH, p = flat - b * NPATCH;
        int ho = p / 24, wo = p - ho * 24;
        *(float4*)(&buf[l][k]) = *(const float4*)(pix +
            (((size_t)b * NC + c) * HH + (size_t)ho * 16 + i) * WW + wo * 16 + j);
    }
    __syncthreads();
    float dy[8], dx[8];
    {
        float a0[8], a1[8];
        float b0 = offb[2 * tid], b1 = offb[2 * tid + 1];
        #pragma unroll
        for (int l = 0; l < 8; ++l) { a0[l] = b0; a1[l] = b1; }
        const float4* w0 = (const float4*)(offw + (size_t)(2 * tid) * PLEN);
        const float4* w1 = w0 + PLEN / 4;
        for (int k4 = 0; k4 < PLEN / 4; ++k4) {
            float4 wa = w0[k4], wb = w1[k4];
            #pragma unroll
            for (int l = 0; l < 8; ++l) {
                float4 pv = *(const float4*)(&buf[l][k4 * 4]);
                a0[l] += wa.x*pv.x + wa.y*pv.y + wa.z*pv.z + wa.w*pv.w;
                a1[l] += wb.x*pv.x + wb.y*pv.y + wb.z*pv.z + wb.w*pv.w;
            }
        }
        #pragma unroll
        for (int l = 0; l < 8; ++l) { dy[l] = a0[l]; dx[l] = a1[l]; }
    }
    __syncthreads();
    {
        const int i = tid >> 4, j = tid & 15;
        #pragma unroll
        for (int l = 0; l < 8; ++l) {
            int flat = loc0 + l, b = flat / NPATCH, p = flat - b * NPATCH;
            int ho = p / 24, wo = p - ho * 24;
            float py = (float)(ho * 16 + i) + dy[l];
            float px = (float)(wo * 16 + j) + dx[l];
            float y0 = floorf(py), x0 = floorf(px);
            float wy1 = py - y0, wy0 = 1.f - wy1, wx1 = px - x0, wx0 = 1.f - wx1;
            const float* pb = pix + (size_t)b * NC * NPIX;
            float s0 = 0, s1 = 0, s2 = 0;
            #pragma unroll
            for (int cy = 0; cy < 2; ++cy)
              #pragma unroll
              for (int cx = 0; cx < 2; ++cx) {
                int yy = (int)y0 + cy, xx = (int)x0 + cx;
                float w = (cy ? wy1 : wy0) * (cx ? wx1 : wx0);
                if ((unsigned)yy < (unsigned)HH && (unsigned)xx < (unsigned)WW) {
                    int idx = yy * WW + xx;
                    s0 += w * pb[idx]; s1 += w * pb[NPIX + idx]; s2 += w * pb[2*NPIX + idx];
                }
              }
            buf[l][tid] = s0; buf[l][256 + tid] = s1; buf[l][512 + tid] = s2;
        }
    }
    __syncthreads();
    {
        float aA[8], aB[8], aC[8];
        float bA = projb[tid], bB = projb[tid + 256], bC = projb[tid + 512];
        #pragma unroll
        for (int l = 0; l < 8; ++l) { aA[l] = bA; aB[l] = bB; aC[l] = bC; }
        const float4* wA = (const float4*)(projw + (size_t)tid * PLEN);
        const float4* wB = (const float4*)(projw + (size_t)(tid + 256) * PLEN);
        const float4* wC = (const float4*)(projw + (size_t)(tid + 512) * PLEN);
        for (int k4 = 0; k4 < PLEN / 4; ++k4) {
            float4 a = wA[k4], bq = wB[k4], cq = wC[k4];
            #pragma unroll
            for (int l = 0; l < 8; ++l) {
                float4 pv = *(const float4*)(&buf[l][k4 * 4]);
                aA[l] += a.x*pv.x + a.y*pv.y + a.z*pv.z + a.w*pv.w;
                aB[l] += bq.x*pv.x + bq.y*pv.y + bq.z*pv.z + bq.w*pv.w;
                aC[l] += cq.x*pv.x + cq.y*pv.y + cq.z*pv.z + cq.w*pv.w;
            }
        }
        #pragma unroll
        for (int l = 0; l < 8; ++l) {
            float* op = out + (size_t)(loc0 + l) * EMB;
            op[tid] = aA[l]; op[tid + 256] = aB[l]; op[tid + 512] = aC[l];
        }
    }
}

extern "C" void kernel_launch(void* const* d_in, const int* in_sizes, int n_in,
                              void* d_out, int out_size, void* d_ws, size_t ws_size,
                              hipStream_t stream) {
    const float* pix   = (const float*)d_in[0];
    const float* offw  = (const float*)d_in[1];
    const float* offb  = (const float*)d_in[2];
    const float* projw = (const float*)d_in[3];
    const float* projb = (const float*)d_in[4];
    float* out = (float*)d_out;
    uint16_t* wz = (uint16_t*)d_ws;

    const size_t ws_needed = (size_t)SA_OFF * 2 + (size_t)NLOC * PLEN * 2;  // ~58.6 MB

    if (ws_size >= ws_needed) {
        uint16_t* sa = wz + SA_OFF;
        prepass_w<<<WBLKS, 256, 0, stream>>>(offw, projw, wz);
        k1_offsets<<<NTILES, 512, 0, stream>>>(pix, offb, wz, sa);
        k2_gather<<<NTILES, 512, 0, stream>>>(pix, sa);
        k3_proj<<<288 * 6, 256, 0, stream>>>(wz, projb, out);
    } else {
        fallback_kernel<<<NLOC / 8, 256, 0, stream>>>(pix, offw, offb, projw, projb, out);
    }
}